// Round 14
// baseline (201.230 us; speedup 1.0000x reference)
//
#include <hip/hip_runtime.h>

// Problem constants (match setup_inputs)
#define BB     4
#define NN     8192
#define DD     128
#define KNN    32
#define BN     (BB*NN)        // 32768 rows total
#define NK     (NN*KNN)       // 262144 edges per batch (2^18)
#define RPB    64             // destination ranges per batch
#define RROWS  128            // rows per range
#define RCAP   4608           // slots per range (mean 4096, +8 sigma)
#define NRANGE (BB*RPB)       // 256 ranges total
#define SCAP   4608           // staging slots per range
#define BCAP   48             // phase-A bucket cap (mean 16, +8 sigma)

typedef float f4 __attribute__((ext_vector_type(4)));   // native vector for nt loads

static __device__ __forceinline__ float inv_denom() { return 1.0f / 32.000001f; }

// ---------------------------------------------------------------------------
// Bmat[e*256 + j]:
//   j <  128 (c=j):     M[c,e] = sum_d Wq[c,d]*Wk[e,d]
//   j >= 128 (o=j-128): P[e,o] = sum_d Wv[e,d]*Wout[d,o]
// Block 0 also zeroes gcursor (stream-ordered before partition_kernel).
// ---------------------------------------------------------------------------
__global__ void compute_bmat(const float* __restrict__ Wqkv,
                             const float* __restrict__ Wout,
                             float* __restrict__ Bmat,
                             int* __restrict__ gcursor) {
    int e = blockIdx.x;      // 0..127
    int j = threadIdx.x;     // 0..255
    if (e == 0) gcursor[j] = 0;          // NRANGE == 256 == blockDim
    float acc = 0.f;
    if (j < DD) {
        int c = j;
        #pragma unroll 4
        for (int d = 0; d < DD; ++d)
            acc += Wqkv[c*3*DD + d] * Wqkv[e*3*DD + DD + d];
    } else {
        int o = j - DD;
        #pragma unroll 4
        for (int d = 0; d < DD; ++d)
            acc += Wqkv[e*3*DD + 2*DD + d] * Wout[d*DD + o];
    }
    Bmat[e*2*DD + j] = acc;
}

// ---------------------------------------------------------------------------
// Phase A: radix partition (each edge scanned once across the grid).
// ---------------------------------------------------------------------------
__global__ __launch_bounds__(256) void partition_kernel(
        const int* __restrict__ idx,
        int* __restrict__ staging,
        int* __restrict__ gcursor) {
    __shared__ int bucket[RPB][BCAP];
    __shared__ int bcnt[RPB];
    __shared__ int gbase[RPB];

    int t  = threadIdx.x;
    int bb = blockIdx.x;
    int batch = bb >> 8;                 // 256 chunks per batch
    int c = bb & 255;
    if (t < RPB) bcnt[t] = 0;
    __syncthreads();

    int4 v = reinterpret_cast<const int4*>(idx)[batch*(NK/4) + c*256 + t];
    int nrow = (c*256 + t) >> 3;         // 8 int4 (32 edges) per source row
    int mm[4] = {v.x, v.y, v.z, v.w};
    #pragma unroll
    for (int j = 0; j < 4; ++j) {
        int m = mm[j];
        int r = m >> 7;
        int p = atomicAdd(&bcnt[r], 1);
        if (p < BCAP) bucket[r][p] = ((m & 127) << 13) | nrow;
    }
    __syncthreads();

    if (t < RPB) {
        int n = min(bcnt[t], BCAP);
        bcnt[t] = n;
        gbase[t] = atomicAdd(&gcursor[batch*RPB + t], n);
    }
    __syncthreads();

    for (int u = t; u < RPB*BCAP; u += 256) {
        int k = u / BCAP, s = u % BCAP;
        if (s < bcnt[k])
            staging[(size_t)(batch*RPB + k)*SCAP + gbase[k] + s] = bucket[k][s];
    }
}

// ---------------------------------------------------------------------------
// Phase B: per-range binning -> srcs16 + packed meta ((off<<8)|cnt).
// ---------------------------------------------------------------------------
__global__ __launch_bounds__(512) void bin_kernel(
        const int* __restrict__ staging,
        const int* __restrict__ gcursor,
        unsigned short* __restrict__ srcs16,
        int* __restrict__ meta) {
    __shared__ unsigned short binned[RCAP];
    __shared__ int hist[RROWS], pfx[RROWS], cur[RROWS];

    int t  = threadIdx.x;
    int rg = blockIdx.x;                 // batch*64 + r
    int cnt = gcursor[rg];
    if (cnt > SCAP) cnt = SCAP;
    const int* sp = staging + (size_t)rg*SCAP;

    if (t < RROWS) { hist[t] = 0; cur[t] = 0; }
    __syncthreads();

    for (int u = t; u < cnt; u += 512)
        atomicAdd(&hist[sp[u] >> 13], 1);
    __syncthreads();

    if (t < 64) {
        int a = hist[2*t], b = hist[2*t+1];
        int s = a + b;
        #pragma unroll
        for (int d = 1; d < 64; d <<= 1) {
            int v = __shfl_up(s, d, 64);
            if (t >= d) s += v;
        }
        int excl = s - (a + b);
        pfx[2*t]   = excl;
        pfx[2*t+1] = excl + a;
    }
    __syncthreads();

    for (int u = t; u < cnt; u += 512) {
        int e = sp[u];
        int ml = e >> 13;
        int p = atomicAdd(&cur[ml], 1);
        binned[pfx[ml] + p] = (unsigned short)(e & 8191);
    }
    __syncthreads();

    int base = rg * RCAP;
    for (int u = t; u < cnt; u += 512) srcs16[base + u] = binned[u];
    if (t < RROWS) {
        int grow = (rg >> 6)*NN + (rg & 63)*RROWS + t;
        meta[grow] = ((base + pfx[t]) << 8) | min(hist[t], 255);
    }
}

// ---------------------------------------------------------------------------
// One diffusion hop, gather form, column-split. 8 static gather slots/lane
// (covers mean cnt=32 exactly) + wave-uniform conditional group of 4
// (cnt<=48, 99.8%) + rare tail. Gathers are NON-TEMPORAL (native f4 vector):
// the 2 MB working set has ~zero L1 reuse per CU, so nt skips L1 allocation
// and relieves the L1 miss-tracking (MSHR) limit modeled at ~49 GB/s/CU.
// ---------------------------------------------------------------------------
__global__ __launch_bounds__(256) void hop_kernel(
        const float* __restrict__ fin, float* __restrict__ fout,
        const int* __restrict__ meta,
        const unsigned short* __restrict__ srcs16) {
    int i = blockIdx.x;                 // 0..16383
    int xcd = i & 7;
    int batch = xcd >> 1, ch = xcd & 1;
    int j = i >> 3;                     // 0..2047
    int wave = threadIdx.x >> 6;
    int lane = threadIdx.x & 63;
    int h = lane >> 4;                  // stream 0..3
    int l16 = lane & 15;
    int g = batch*NN + j*4 + wave;      // global dest row

    int mt = meta[g];
    int off = mt >> 8, cnt = mt & 255;
    const unsigned short* sp = srcs16 + off;
    const float* fbatch = fin + (size_t)batch*NN*DD;
    int laneoff = ch*64 + l16*4;

    int ss[8];
    #pragma unroll
    for (int u = 0; u < 8; ++u) {
        int s = sp[h + 4*u];
        ss[u] = (s > NN-1) ? 0 : s;
    }
    f4 vv[8];
    #pragma unroll
    for (int u = 0; u < 8; ++u)
        vv[u] = __builtin_nontemporal_load(
            reinterpret_cast<const f4*>(fbatch + ss[u]*DD + laneoff));
    f4 acc = (f4){0.f, 0.f, 0.f, 0.f};
    #pragma unroll
    for (int u = 0; u < 8; ++u) {
        float mwt = (h + 4*u < cnt) ? 1.f : 0.f;
        acc += vv[u] * mwt;
    }
    if (cnt > 32) {                      // wave-uniform branch
        int s2[4];
        #pragma unroll
        for (int u = 0; u < 4; ++u) {
            int s = sp[32 + h + 4*u];
            s2[u] = (s > NN-1) ? 0 : s;
        }
        f4 v2[4];
        #pragma unroll
        for (int u = 0; u < 4; ++u)
            v2[u] = __builtin_nontemporal_load(
                reinterpret_cast<const f4*>(fbatch + s2[u]*DD + laneoff));
        #pragma unroll
        for (int u = 0; u < 4; ++u) {
            float mwt = (32 + h + 4*u < cnt) ? 1.f : 0.f;
            acc += v2[u] * mwt;
        }
        for (int e = 48 + h; e < cnt; e += 4) {
            int s = sp[e];
            f4 v = __builtin_nontemporal_load(
                reinterpret_cast<const f4*>(fbatch + s*DD + laneoff));
            acc += v;
        }
    }

    acc.x += __shfl_xor(acc.x, 16); acc.y += __shfl_xor(acc.y, 16);
    acc.z += __shfl_xor(acc.z, 16); acc.w += __shfl_xor(acc.w, 16);
    acc.x += __shfl_xor(acc.x, 32); acc.y += __shfl_xor(acc.y, 32);
    acc.z += __shfl_xor(acc.z, 32); acc.w += __shfl_xor(acc.w, 32);

    if (h == 0) {
        const float s = inv_denom();
        float4 o = make_float4(acc.x*s, acc.y*s, acc.z*s, acc.w*s);
        *reinterpret_cast<float4*>(fout + (size_t)g*DD + laneoff) = o;
    }
}

// ---------------------------------------------------------------------------
// Fused final stage, 64-row tiles (8x8 acc) with explicit register
// double-buffer prefetch of Bmat k-chunks (R11 version, proven).
// ---------------------------------------------------------------------------
__global__ __launch_bounds__(256) void final_kernel(
        const float* __restrict__ x3, const float* __restrict__ x,
        const float* __restrict__ Bmat, const float* __restrict__ bout,
        float* __restrict__ out) {
    __shared__ float a_lds[64][DD];
    __shared__ float attn_lds[64];
    int t = threadIdx.x;
    int tc = t & 31, tr = t >> 5;       // tc: 8 cols each; tr: 8 rows each
    int row0 = blockIdx.x * 64;

    for (int u = t; u < 64*32; u += 256) {
        int r = u >> 5, cp = u & 31;
        *reinterpret_cast<float4*>(&a_lds[r][cp*4]) =
            *reinterpret_cast<const float4*>(x3 + (size_t)(row0 + r)*DD + cp*4);
    }
    if (t < 64) attn_lds[t] = 0.f;

    const float* bp = Bmat + tc*8;      // this thread's column slice
    float4 pa0[4], pa1[4], pb0[4], pb1[4];
    #pragma unroll
    for (int kk = 0; kk < 4; ++kk) {
        pa0[kk] = *reinterpret_cast<const float4*>(bp + kk*256);
        pa1[kk] = *reinterpret_cast<const float4*>(bp + kk*256 + 4);
    }
    __syncthreads();

    float acc[8][8];
    #pragma unroll
    for (int r = 0; r < 8; ++r)
        #pragma unroll
        for (int u = 0; u < 8; ++u) acc[r][u] = 0.f;

    #pragma unroll 1
    for (int k0 = 0; k0 < DD; k0 += 8) {
        int kn = (k0 + 4 < DD) ? (k0 + 4) : 0;
        #pragma unroll
        for (int kk = 0; kk < 4; ++kk) {
            pb0[kk] = *reinterpret_cast<const float4*>(bp + (kn+kk)*256);
            pb1[kk] = *reinterpret_cast<const float4*>(bp + (kn+kk)*256 + 4);
        }
        {
            float4 av[8];
            #pragma unroll
            for (int r = 0; r < 8; ++r)
                av[r] = *reinterpret_cast<const float4*>(&a_lds[tr*8 + r][k0]);
            #pragma unroll
            for (int kk = 0; kk < 4; ++kk) {
                #pragma unroll
                for (int r = 0; r < 8; ++r) {
                    float a = (kk == 0) ? av[r].x : (kk == 1) ? av[r].y
                            : (kk == 2) ? av[r].z : av[r].w;
                    acc[r][0] += a*pa0[kk].x; acc[r][1] += a*pa0[kk].y;
                    acc[r][2] += a*pa0[kk].z; acc[r][3] += a*pa0[kk].w;
                    acc[r][4] += a*pa1[kk].x; acc[r][5] += a*pa1[kk].y;
                    acc[r][6] += a*pa1[kk].z; acc[r][7] += a*pa1[kk].w;
                }
            }
        }
        int km = (k0 + 8 < DD) ? (k0 + 8) : 0;
        #pragma unroll
        for (int kk = 0; kk < 4; ++kk) {
            pa0[kk] = *reinterpret_cast<const float4*>(bp + (km+kk)*256);
            pa1[kk] = *reinterpret_cast<const float4*>(bp + (km+kk)*256 + 4);
        }
        {
            float4 av[8];
            #pragma unroll
            for (int r = 0; r < 8; ++r)
                av[r] = *reinterpret_cast<const float4*>(&a_lds[tr*8 + r][k0 + 4]);
            #pragma unroll
            for (int kk = 0; kk < 4; ++kk) {
                #pragma unroll
                for (int r = 0; r < 8; ++r) {
                    float a = (kk == 0) ? av[r].x : (kk == 1) ? av[r].y
                            : (kk == 2) ? av[r].z : av[r].w;
                    acc[r][0] += a*pb0[kk].x; acc[r][1] += a*pb0[kk].y;
                    acc[r][2] += a*pb0[kk].z; acc[r][3] += a*pb0[kk].w;
                    acc[r][4] += a*pb1[kk].x; acc[r][5] += a*pb1[kk].y;
                    acc[r][6] += a*pb1[kk].z; acc[r][7] += a*pb1[kk].w;
                }
            }
        }
    }

    if (tc < 16) {
        #pragma unroll
        for (int r = 0; r < 8; ++r) {
            int row = row0 + tr*8 + r;
            const float4 xa = *reinterpret_cast<const float4*>(x + (size_t)row*DD + tc*8);
            const float4 xb = *reinterpret_cast<const float4*>(x + (size_t)row*DD + tc*8 + 4);
            float p = xa.x*acc[r][0] + xa.y*acc[r][1] + xa.z*acc[r][2] + xa.w*acc[r][3]
                    + xb.x*acc[r][4] + xb.y*acc[r][5] + xb.z*acc[r][6] + xb.w*acc[r][7];
            atomicAdd(&attn_lds[tr*8 + r], p);
        }
    }
    __syncthreads();

    if (tc >= 16) {
        int c0 = (tc - 16) * 8;
        float4 ba  = *reinterpret_cast<const float4*>(bout + c0);
        float4 bbv = *reinterpret_cast<const float4*>(bout + c0 + 4);
        #pragma unroll
        for (int r = 0; r < 8; ++r) {
            int row = row0 + tr*8 + r;
            float at = attn_lds[tr*8 + r];
            float4 o0, o1;
            o0.x = at*acc[r][0] + ba.x;  o0.y = at*acc[r][1] + ba.y;
            o0.z = at*acc[r][2] + ba.z;  o0.w = at*acc[r][3] + ba.w;
            o1.x = at*acc[r][4] + bbv.x; o1.y = at*acc[r][5] + bbv.y;
            o1.z = at*acc[r][6] + bbv.z; o1.w = at*acc[r][7] + bbv.w;
            *reinterpret_cast<float4*>(out + (size_t)row*DD + c0)     = o0;
            *reinterpret_cast<float4*>(out + (size_t)row*DD + c0 + 4) = o1;
        }
    }
}

// ---------------------------------------------------------------------------
// ws layout (~24.3 MB; measured ws_size ~268 MB):
//   f_a     @ 0         16777216 B   (x3 ping buffer)
//   srcs16  @ 16777216   2359552 B   (256*4608 u16 + pad)
//   meta    @ 19136768    131072 B   (packed (off<<8)|cnt)
//   (spare) @ 19267840    131072 B
//   Bmat    @ 19398912    131072 B
//   staging @ 19529984   4718592 B   (256*4608 int)
//   gcursor @ 24248576      1024 B
// ---------------------------------------------------------------------------
extern "C" void kernel_launch(void* const* d_in, const int* in_sizes, int n_in,
                              void* d_out, int out_size, void* d_ws, size_t ws_size,
                              hipStream_t stream) {
    const float* x    = (const float*)d_in[0];
    const int*   idx  = (const int*)  d_in[1];
    const float* Wqkv = (const float*)d_in[2];
    const float* Wout = (const float*)d_in[3];
    const float* bout = (const float*)d_in[4];
    float* out = (float*)d_out;

    char* ws = (char*)d_ws;
    float*          f_a     = (float*)(ws);
    unsigned short* srcs16  = (unsigned short*)(ws + 16777216);
    int*            meta    = (int*)(ws + 19136768);
    float*          Bmat    = (float*)(ws + 19398912);
    int*            staging = (int*)(ws + 19529984);
    int*            gcursor = (int*)(ws + 24248576);

    compute_bmat<<<DD, 256, 0, stream>>>(Wqkv, Wout, Bmat, gcursor);
    partition_kernel<<<1024, 256, 0, stream>>>(idx, staging, gcursor);
    bin_kernel<<<NRANGE, 512, 0, stream>>>(staging, gcursor, srcs16, meta);

    hop_kernel<<<16384, 256, 0, stream>>>(x,   f_a, meta, srcs16);
    hop_kernel<<<16384, 256, 0, stream>>>(f_a, out, meta, srcs16);
    hop_kernel<<<16384, 256, 0, stream>>>(out, f_a, meta, srcs16);

    final_kernel<<<BN/64, 256, 0, stream>>>(f_a, x, Bmat, bout, out);
}

// Round 15
// 159.941 us; speedup vs baseline: 1.2582x; 1.2582x over previous
//
#include <hip/hip_runtime.h>

// Problem constants (match setup_inputs)
#define BB     4
#define NN     8192
#define DD     128
#define KNN    32
#define BN     (BB*NN)        // 32768 rows total
#define NK     (NN*KNN)       // 262144 edges per batch (2^18)
#define RPB    64             // destination ranges per batch
#define RROWS  128            // rows per range
#define RCAP   4608           // slots per range (mean 4096, +8 sigma)
#define NRANGE (BB*RPB)       // 256 ranges total
#define SCAP   4608           // staging slots per range
#define BCAP   48             // phase-A bucket cap (mean 16, +8 sigma)

static __device__ __forceinline__ float inv_denom() { return 1.0f / 32.000001f; }

// ---------------------------------------------------------------------------
// Bmat[e*256 + j]:
//   j <  128 (c=j):     M[c,e] = sum_d Wq[c,d]*Wk[e,d]
//   j >= 128 (o=j-128): P[e,o] = sum_d Wv[e,d]*Wout[d,o]
// Block 0 also zeroes gcursor (stream-ordered before partition_kernel).
// ---------------------------------------------------------------------------
__global__ void compute_bmat(const float* __restrict__ Wqkv,
                             const float* __restrict__ Wout,
                             float* __restrict__ Bmat,
                             int* __restrict__ gcursor) {
    int e = blockIdx.x;      // 0..127
    int j = threadIdx.x;     // 0..255
    if (e == 0) gcursor[j] = 0;          // NRANGE == 256 == blockDim
    float acc = 0.f;
    if (j < DD) {
        int c = j;
        #pragma unroll 4
        for (int d = 0; d < DD; ++d)
            acc += Wqkv[c*3*DD + d] * Wqkv[e*3*DD + DD + d];
    } else {
        int o = j - DD;
        #pragma unroll 4
        for (int d = 0; d < DD; ++d)
            acc += Wqkv[e*3*DD + 2*DD + d] * Wout[d*DD + o];
    }
    Bmat[e*2*DD + j] = acc;
}

// ---------------------------------------------------------------------------
// Phase A: radix partition (each edge scanned once across the grid).
// ---------------------------------------------------------------------------
__global__ __launch_bounds__(256) void partition_kernel(
        const int* __restrict__ idx,
        int* __restrict__ staging,
        int* __restrict__ gcursor) {
    __shared__ int bucket[RPB][BCAP];
    __shared__ int bcnt[RPB];
    __shared__ int gbase[RPB];

    int t  = threadIdx.x;
    int bb = blockIdx.x;
    int batch = bb >> 8;                 // 256 chunks per batch
    int c = bb & 255;
    if (t < RPB) bcnt[t] = 0;
    __syncthreads();

    int4 v = reinterpret_cast<const int4*>(idx)[batch*(NK/4) + c*256 + t];
    int nrow = (c*256 + t) >> 3;         // 8 int4 (32 edges) per source row
    int mm[4] = {v.x, v.y, v.z, v.w};
    #pragma unroll
    for (int j = 0; j < 4; ++j) {
        int m = mm[j];
        int r = m >> 7;
        int p = atomicAdd(&bcnt[r], 1);
        if (p < BCAP) bucket[r][p] = ((m & 127) << 13) | nrow;
    }
    __syncthreads();

    if (t < RPB) {
        int n = min(bcnt[t], BCAP);
        bcnt[t] = n;
        gbase[t] = atomicAdd(&gcursor[batch*RPB + t], n);
    }
    __syncthreads();

    for (int u = t; u < RPB*BCAP; u += 256) {
        int k = u / BCAP, s = u % BCAP;
        if (s < bcnt[k])
            staging[(size_t)(batch*RPB + k)*SCAP + gbase[k] + s] = bucket[k][s];
    }
}

// ---------------------------------------------------------------------------
// Phase B: per-range binning -> srcs16 + packed meta ((off<<8)|cnt).
// ---------------------------------------------------------------------------
__global__ __launch_bounds__(512) void bin_kernel(
        const int* __restrict__ staging,
        const int* __restrict__ gcursor,
        unsigned short* __restrict__ srcs16,
        int* __restrict__ meta) {
    __shared__ unsigned short binned[RCAP];
    __shared__ int hist[RROWS], pfx[RROWS], cur[RROWS];

    int t  = threadIdx.x;
    int rg = blockIdx.x;                 // batch*64 + r
    int cnt = gcursor[rg];
    if (cnt > SCAP) cnt = SCAP;
    const int* sp = staging + (size_t)rg*SCAP;

    if (t < RROWS) { hist[t] = 0; cur[t] = 0; }
    __syncthreads();

    for (int u = t; u < cnt; u += 512)
        atomicAdd(&hist[sp[u] >> 13], 1);
    __syncthreads();

    if (t < 64) {
        int a = hist[2*t], b = hist[2*t+1];
        int s = a + b;
        #pragma unroll
        for (int d = 1; d < 64; d <<= 1) {
            int v = __shfl_up(s, d, 64);
            if (t >= d) s += v;
        }
        int excl = s - (a + b);
        pfx[2*t]   = excl;
        pfx[2*t+1] = excl + a;
    }
    __syncthreads();

    for (int u = t; u < cnt; u += 512) {
        int e = sp[u];
        int ml = e >> 13;
        int p = atomicAdd(&cur[ml], 1);
        binned[pfx[ml] + p] = (unsigned short)(e & 8191);
    }
    __syncthreads();

    int base = rg * RCAP;
    for (int u = t; u < cnt; u += 512) srcs16[base + u] = binned[u];
    if (t < RROWS) {
        int grow = (rg >> 6)*NN + (rg & 63)*RROWS + t;
        meta[grow] = ((base + pfx[t]) << 8) | min(hist[t], 255);
    }
}

// ---------------------------------------------------------------------------
// One diffusion hop, gather form, column-split. Plain (cached) loads — nt
// was measured harmful (FETCH 10.4->18.7 MB, no speedup). 8 static slots
// always; 4 more issued EAGERLY under a wave-uniform cnt>32 branch (cnt is
// per-row, uniform across the wave) so all 12 are in flight concurrently;
// per-lane tail only beyond 48 (0.2% of rows).
// ---------------------------------------------------------------------------
__global__ __launch_bounds__(256) void hop_kernel(
        const float* __restrict__ fin, float* __restrict__ fout,
        const int* __restrict__ meta,
        const unsigned short* __restrict__ srcs16) {
    int i = blockIdx.x;                 // 0..16383
    int xcd = i & 7;
    int batch = xcd >> 1, ch = xcd & 1;
    int j = i >> 3;                     // 0..2047
    int wave = threadIdx.x >> 6;
    int lane = threadIdx.x & 63;
    int h = lane >> 4;                  // stream 0..3
    int l16 = lane & 15;
    int g = batch*NN + j*4 + wave;      // global dest row

    int mt = meta[g];
    int off = mt >> 8, cnt = mt & 255;
    const unsigned short* sp = srcs16 + off;
    const float* fbatch = fin + (size_t)batch*NN*DD;
    int laneoff = ch*64 + l16*4;

    // issue all gathers eagerly: 8 always, +4 if cnt>32 (wave-uniform)
    int ss[8];
    #pragma unroll
    for (int u = 0; u < 8; ++u) {
        int s = sp[h + 4*u];
        ss[u] = (s > NN-1) ? 0 : s;
    }
    float4 vv[8];
    #pragma unroll
    for (int u = 0; u < 8; ++u)
        vv[u] = *reinterpret_cast<const float4*>(fbatch + ss[u]*DD + laneoff);

    float4 acc = make_float4(0.f, 0.f, 0.f, 0.f);
    bool big = (cnt > 32);
    float4 v2[4];
    if (big) {
        int s2[4];
        #pragma unroll
        for (int u = 0; u < 4; ++u) {
            int s = sp[32 + h + 4*u];
            s2[u] = (s > NN-1) ? 0 : s;
        }
        #pragma unroll
        for (int u = 0; u < 4; ++u)
            v2[u] = *reinterpret_cast<const float4*>(fbatch + s2[u]*DD + laneoff);
    }

    #pragma unroll
    for (int u = 0; u < 8; ++u) {
        float mwt = (h + 4*u < cnt) ? 1.f : 0.f;
        acc.x += vv[u].x * mwt; acc.y += vv[u].y * mwt;
        acc.z += vv[u].z * mwt; acc.w += vv[u].w * mwt;
    }
    if (big) {
        #pragma unroll
        for (int u = 0; u < 4; ++u) {
            float mwt = (32 + h + 4*u < cnt) ? 1.f : 0.f;
            acc.x += v2[u].x * mwt; acc.y += v2[u].y * mwt;
            acc.z += v2[u].z * mwt; acc.w += v2[u].w * mwt;
        }
        for (int e = 48 + h; e < cnt; e += 4) {
            int s = sp[e];
            float4 v = *reinterpret_cast<const float4*>(fbatch + s*DD + laneoff);
            acc.x += v.x; acc.y += v.y; acc.z += v.z; acc.w += v.w;
        }
    }

    acc.x += __shfl_xor(acc.x, 16); acc.y += __shfl_xor(acc.y, 16);
    acc.z += __shfl_xor(acc.z, 16); acc.w += __shfl_xor(acc.w, 16);
    acc.x += __shfl_xor(acc.x, 32); acc.y += __shfl_xor(acc.y, 32);
    acc.z += __shfl_xor(acc.z, 32); acc.w += __shfl_xor(acc.w, 32);

    if (h == 0) {
        const float s = inv_denom();
        float4 o = make_float4(acc.x*s, acc.y*s, acc.z*s, acc.w*s);
        *reinterpret_cast<float4*>(fout + (size_t)g*DD + laneoff) = o;
    }
}

// ---------------------------------------------------------------------------
// Fused final stage: 64x256 tile at 512 THREADS (thread = 4 rows x 8 cols),
// 8 waves/block, 2 blocks/CU = 4 waves/SIMD (was 2 — grid-limited at 14%
// occupancy). Register double-buffer prefetch of Bmat k-chunks retained.
// ---------------------------------------------------------------------------
__global__ __launch_bounds__(512) void final_kernel(
        const float* __restrict__ x3, const float* __restrict__ x,
        const float* __restrict__ Bmat, const float* __restrict__ bout,
        float* __restrict__ out) {
    __shared__ float a_lds[64][DD];
    __shared__ float attn_lds[64];
    int t = threadIdx.x;
    int tc = t & 31, tr = t >> 5;       // tc: 8 cols each of 256; tr: 0..15, 4 rows each
    int row0 = blockIdx.x * 64;

    for (int u = t; u < 64*32; u += 512) {
        int r = u >> 5, cp = u & 31;
        *reinterpret_cast<float4*>(&a_lds[r][cp*4]) =
            *reinterpret_cast<const float4*>(x3 + (size_t)(row0 + r)*DD + cp*4);
    }
    if (t < 64) attn_lds[t] = 0.f;

    const float* bp = Bmat + tc*8;      // this thread's column slice
    float4 pa0[4], pa1[4], pb0[4], pb1[4];
    #pragma unroll
    for (int kk = 0; kk < 4; ++kk) {
        pa0[kk] = *reinterpret_cast<const float4*>(bp + kk*256);
        pa1[kk] = *reinterpret_cast<const float4*>(bp + kk*256 + 4);
    }
    __syncthreads();

    float acc[4][8];
    #pragma unroll
    for (int r = 0; r < 4; ++r)
        #pragma unroll
        for (int u = 0; u < 8; ++u) acc[r][u] = 0.f;

    #pragma unroll 1
    for (int k0 = 0; k0 < DD; k0 += 8) {
        int kn = (k0 + 4 < DD) ? (k0 + 4) : 0;
        #pragma unroll
        for (int kk = 0; kk < 4; ++kk) {
            pb0[kk] = *reinterpret_cast<const float4*>(bp + (kn+kk)*256);
            pb1[kk] = *reinterpret_cast<const float4*>(bp + (kn+kk)*256 + 4);
        }
        {
            float4 av[4];
            #pragma unroll
            for (int r = 0; r < 4; ++r)
                av[r] = *reinterpret_cast<const float4*>(&a_lds[tr*4 + r][k0]);
            #pragma unroll
            for (int kk = 0; kk < 4; ++kk) {
                #pragma unroll
                for (int r = 0; r < 4; ++r) {
                    float a = (kk == 0) ? av[r].x : (kk == 1) ? av[r].y
                            : (kk == 2) ? av[r].z : av[r].w;
                    acc[r][0] += a*pa0[kk].x; acc[r][1] += a*pa0[kk].y;
                    acc[r][2] += a*pa0[kk].z; acc[r][3] += a*pa0[kk].w;
                    acc[r][4] += a*pa1[kk].x; acc[r][5] += a*pa1[kk].y;
                    acc[r][6] += a*pa1[kk].z; acc[r][7] += a*pa1[kk].w;
                }
            }
        }
        int km = (k0 + 8 < DD) ? (k0 + 8) : 0;
        #pragma unroll
        for (int kk = 0; kk < 4; ++kk) {
            pa0[kk] = *reinterpret_cast<const float4*>(bp + (km+kk)*256);
            pa1[kk] = *reinterpret_cast<const float4*>(bp + (km+kk)*256 + 4);
        }
        {
            float4 av[4];
            #pragma unroll
            for (int r = 0; r < 4; ++r)
                av[r] = *reinterpret_cast<const float4*>(&a_lds[tr*4 + r][k0 + 4]);
            #pragma unroll
            for (int kk = 0; kk < 4; ++kk) {
                #pragma unroll
                for (int r = 0; r < 4; ++r) {
                    float a = (kk == 0) ? av[r].x : (kk == 1) ? av[r].y
                            : (kk == 2) ? av[r].z : av[r].w;
                    acc[r][0] += a*pb0[kk].x; acc[r][1] += a*pb0[kk].y;
                    acc[r][2] += a*pb0[kk].z; acc[r][3] += a*pb0[kk].w;
                    acc[r][4] += a*pb1[kk].x; acc[r][5] += a*pb1[kk].y;
                    acc[r][6] += a*pb1[kk].z; acc[r][7] += a*pb1[kk].w;
                }
            }
        }
    }

    if (tc < 16) {
        #pragma unroll
        for (int r = 0; r < 4; ++r) {
            int row = row0 + tr*4 + r;
            const float4 xa = *reinterpret_cast<const float4*>(x + (size_t)row*DD + tc*8);
            const float4 xb = *reinterpret_cast<const float4*>(x + (size_t)row*DD + tc*8 + 4);
            float p = xa.x*acc[r][0] + xa.y*acc[r][1] + xa.z*acc[r][2] + xa.w*acc[r][3]
                    + xb.x*acc[r][4] + xb.y*acc[r][5] + xb.z*acc[r][6] + xb.w*acc[r][7];
            atomicAdd(&attn_lds[tr*4 + r], p);
        }
    }
    __syncthreads();

    if (tc >= 16) {
        int c0 = (tc - 16) * 8;
        float4 ba  = *reinterpret_cast<const float4*>(bout + c0);
        float4 bbv = *reinterpret_cast<const float4*>(bout + c0 + 4);
        #pragma unroll
        for (int r = 0; r < 4; ++r) {
            int row = row0 + tr*4 + r;
            float at = attn_lds[tr*4 + r];
            float4 o0, o1;
            o0.x = at*acc[r][0] + ba.x;  o0.y = at*acc[r][1] + ba.y;
            o0.z = at*acc[r][2] + ba.z;  o0.w = at*acc[r][3] + ba.w;
            o1.x = at*acc[r][4] + bbv.x; o1.y = at*acc[r][5] + bbv.y;
            o1.z = at*acc[r][6] + bbv.z; o1.w = at*acc[r][7] + bbv.w;
            *reinterpret_cast<float4*>(out + (size_t)row*DD + c0)     = o0;
            *reinterpret_cast<float4*>(out + (size_t)row*DD + c0 + 4) = o1;
        }
    }
}

// ---------------------------------------------------------------------------
// ws layout (~24.3 MB; measured ws_size ~268 MB):
//   f_a     @ 0         16777216 B   (x3 ping buffer)
//   srcs16  @ 16777216   2359552 B   (256*4608 u16 + pad)
//   meta    @ 19136768    131072 B   (packed (off<<8)|cnt)
//   (spare) @ 19267840    131072 B
//   Bmat    @ 19398912    131072 B
//   staging @ 19529984   4718592 B   (256*4608 int)
//   gcursor @ 24248576      1024 B
// ---------------------------------------------------------------------------
extern "C" void kernel_launch(void* const* d_in, const int* in_sizes, int n_in,
                              void* d_out, int out_size, void* d_ws, size_t ws_size,
                              hipStream_t stream) {
    const float* x    = (const float*)d_in[0];
    const int*   idx  = (const int*)  d_in[1];
    const float* Wqkv = (const float*)d_in[2];
    const float* Wout = (const float*)d_in[3];
    const float* bout = (const float*)d_in[4];
    float* out = (float*)d_out;

    char* ws = (char*)d_ws;
    float*          f_a     = (float*)(ws);
    unsigned short* srcs16  = (unsigned short*)(ws + 16777216);
    int*            meta    = (int*)(ws + 19136768);
    float*          Bmat    = (float*)(ws + 19398912);
    int*            staging = (int*)(ws + 19529984);
    int*            gcursor = (int*)(ws + 24248576);

    compute_bmat<<<DD, 256, 0, stream>>>(Wqkv, Wout, Bmat, gcursor);
    partition_kernel<<<1024, 256, 0, stream>>>(idx, staging, gcursor);
    bin_kernel<<<NRANGE, 512, 0, stream>>>(staging, gcursor, srcs16, meta);

    hop_kernel<<<16384, 256, 0, stream>>>(x,   f_a, meta, srcs16);
    hop_kernel<<<16384, 256, 0, stream>>>(f_a, out, meta, srcs16);
    hop_kernel<<<16384, 256, 0, stream>>>(out, f_a, meta, srcs16);

    final_kernel<<<BN/64, 512, 0, stream>>>(f_a, x, Bmat, bout, out);
}

// Round 16
// 156.236 us; speedup vs baseline: 1.2880x; 1.0237x over previous
//
#include <hip/hip_runtime.h>

// Problem constants (match setup_inputs)
#define BB     4
#define NN     8192
#define DD     128
#define KNN    32
#define BN     (BB*NN)        // 32768 rows total
#define NK     (NN*KNN)       // 262144 edges per batch (2^18)
#define RPB    64             // destination ranges per batch
#define RROWS  128            // rows per range
#define RCAP   4608           // slots per range (mean 4096, +8 sigma)
#define NRANGE (BB*RPB)       // 256 ranges total
#define SCAP   4608           // staging slots per range
#define BCAP   48             // phase-A bucket cap (mean 16, +8 sigma)

static __device__ __forceinline__ float inv_denom() { return 1.0f / 32.000001f; }

// ---------------------------------------------------------------------------
// Bmat[e*256 + j]:
//   j <  128 (c=j):     M[c,e] = sum_d Wq[c,d]*Wk[e,d]
//   j >= 128 (o=j-128): P[e,o] = sum_d Wv[e,d]*Wout[d,o]
// Block 0 also zeroes gcursor (stream-ordered before partition_kernel).
// ---------------------------------------------------------------------------
__global__ void compute_bmat(const float* __restrict__ Wqkv,
                             const float* __restrict__ Wout,
                             float* __restrict__ Bmat,
                             int* __restrict__ gcursor) {
    int e = blockIdx.x;      // 0..127
    int j = threadIdx.x;     // 0..255
    if (e == 0) gcursor[j] = 0;          // NRANGE == 256 == blockDim
    float acc = 0.f;
    if (j < DD) {
        int c = j;
        #pragma unroll 4
        for (int d = 0; d < DD; ++d)
            acc += Wqkv[c*3*DD + d] * Wqkv[e*3*DD + DD + d];
    } else {
        int o = j - DD;
        #pragma unroll 4
        for (int d = 0; d < DD; ++d)
            acc += Wqkv[e*3*DD + 2*DD + d] * Wout[d*DD + o];
    }
    Bmat[e*2*DD + j] = acc;
}

// ---------------------------------------------------------------------------
// Phase A: radix partition (each edge scanned once across the grid).
// ---------------------------------------------------------------------------
__global__ __launch_bounds__(256) void partition_kernel(
        const int* __restrict__ idx,
        int* __restrict__ staging,
        int* __restrict__ gcursor) {
    __shared__ int bucket[RPB][BCAP];
    __shared__ int bcnt[RPB];
    __shared__ int gbase[RPB];

    int t  = threadIdx.x;
    int bb = blockIdx.x;
    int batch = bb >> 8;                 // 256 chunks per batch
    int c = bb & 255;
    if (t < RPB) bcnt[t] = 0;
    __syncthreads();

    int4 v = reinterpret_cast<const int4*>(idx)[batch*(NK/4) + c*256 + t];
    int nrow = (c*256 + t) >> 3;         // 8 int4 (32 edges) per source row
    int mm[4] = {v.x, v.y, v.z, v.w};
    #pragma unroll
    for (int j = 0; j < 4; ++j) {
        int m = mm[j];
        int r = m >> 7;
        int p = atomicAdd(&bcnt[r], 1);
        if (p < BCAP) bucket[r][p] = ((m & 127) << 13) | nrow;
    }
    __syncthreads();

    if (t < RPB) {
        int n = min(bcnt[t], BCAP);
        bcnt[t] = n;
        gbase[t] = atomicAdd(&gcursor[batch*RPB + t], n);
    }
    __syncthreads();

    for (int u = t; u < RPB*BCAP; u += 256) {
        int k = u / BCAP, s = u % BCAP;
        if (s < bcnt[k])
            staging[(size_t)(batch*RPB + k)*SCAP + gbase[k] + s] = bucket[k][s];
    }
}

// ---------------------------------------------------------------------------
// Phase B: per-range binning -> srcs16 + packed meta ((off<<8)|cnt).
// ---------------------------------------------------------------------------
__global__ __launch_bounds__(512) void bin_kernel(
        const int* __restrict__ staging,
        const int* __restrict__ gcursor,
        unsigned short* __restrict__ srcs16,
        int* __restrict__ meta) {
    __shared__ unsigned short binned[RCAP];
    __shared__ int hist[RROWS], pfx[RROWS], cur[RROWS];

    int t  = threadIdx.x;
    int rg = blockIdx.x;                 // batch*64 + r
    int cnt = gcursor[rg];
    if (cnt > SCAP) cnt = SCAP;
    const int* sp = staging + (size_t)rg*SCAP;

    if (t < RROWS) { hist[t] = 0; cur[t] = 0; }
    __syncthreads();

    for (int u = t; u < cnt; u += 512)
        atomicAdd(&hist[sp[u] >> 13], 1);
    __syncthreads();

    if (t < 64) {
        int a = hist[2*t], b = hist[2*t+1];
        int s = a + b;
        #pragma unroll
        for (int d = 1; d < 64; d <<= 1) {
            int v = __shfl_up(s, d, 64);
            if (t >= d) s += v;
        }
        int excl = s - (a + b);
        pfx[2*t]   = excl;
        pfx[2*t+1] = excl + a;
    }
    __syncthreads();

    for (int u = t; u < cnt; u += 512) {
        int e = sp[u];
        int ml = e >> 13;
        int p = atomicAdd(&cur[ml], 1);
        binned[pfx[ml] + p] = (unsigned short)(e & 8191);
    }
    __syncthreads();

    int base = rg * RCAP;
    for (int u = t; u < cnt; u += 512) srcs16[base + u] = binned[u];
    if (t < RROWS) {
        int grow = (rg >> 6)*NN + (rg & 63)*RROWS + t;
        meta[grow] = ((base + pfx[t]) << 8) | min(hist[t], 255);
    }
}

// ---------------------------------------------------------------------------
// One diffusion hop, gather form, column-split, TWO ROWS PER WAVE:
// both rows' meta/slots loaded up front, 16 gathers (24 with big rows)
// issued back-to-back -> 2x memory-level parallelism per wave at similar
// occupancy. Discriminates latency-bound (expect ~2x) vs L2-request-rate-
// bound (expect null). Plain cached loads (nt measured harmful, R14).
// ---------------------------------------------------------------------------
__global__ __launch_bounds__(256) void hop_kernel(
        const float* __restrict__ fin, float* __restrict__ fout,
        const int* __restrict__ meta,
        const unsigned short* __restrict__ srcs16) {
    int i = blockIdx.x;                 // 0..8191
    int xcd = i & 7;
    int batch = xcd >> 1, ch = xcd & 1;
    int j = i >> 3;                     // 0..1023
    int wave = threadIdx.x >> 6;
    int lane = threadIdx.x & 63;
    int h = lane >> 4;                  // stream 0..3
    int l16 = lane & 15;
    int g0 = batch*NN + j*8 + wave*2;   // rows g0 and g0+1

    int mt0 = meta[g0], mt1 = meta[g0 + 1];
    int off0 = mt0 >> 8, cnt0 = mt0 & 255;
    int off1 = mt1 >> 8, cnt1 = mt1 & 255;
    const unsigned short* sp0 = srcs16 + off0;
    const unsigned short* sp1 = srcs16 + off1;
    const float* fbatch = fin + (size_t)batch*NN*DD;
    int laneoff = ch*64 + l16*4;

    // slot ids for both rows (independent small loads, all in flight)
    int sA[8], sB[8];
    #pragma unroll
    for (int u = 0; u < 8; ++u) {
        int a = sp0[h + 4*u]; sA[u] = (a > NN-1) ? 0 : a;
        int b = sp1[h + 4*u]; sB[u] = (b > NN-1) ? 0 : b;
    }
    // 16 independent gathers back-to-back
    float4 vA[8], vB[8];
    #pragma unroll
    for (int u = 0; u < 8; ++u)
        vA[u] = *reinterpret_cast<const float4*>(fbatch + sA[u]*DD + laneoff);
    #pragma unroll
    for (int u = 0; u < 8; ++u)
        vB[u] = *reinterpret_cast<const float4*>(fbatch + sB[u]*DD + laneoff);

    float4 acc0 = make_float4(0.f,0.f,0.f,0.f);
    float4 acc1 = make_float4(0.f,0.f,0.f,0.f);
    #pragma unroll
    for (int u = 0; u < 8; ++u) {
        float m0 = (h + 4*u < cnt0) ? 1.f : 0.f;
        float m1 = (h + 4*u < cnt1) ? 1.f : 0.f;
        acc0.x += vA[u].x*m0; acc0.y += vA[u].y*m0;
        acc0.z += vA[u].z*m0; acc0.w += vA[u].w*m0;
        acc1.x += vB[u].x*m1; acc1.y += vB[u].y*m1;
        acc1.z += vB[u].z*m1; acc1.w += vB[u].w*m1;
    }

    if (cnt0 > 32) {                     // wave-uniform
        float4 v2[4]; int s2[4];
        #pragma unroll
        for (int u = 0; u < 4; ++u) {
            int s = sp0[32 + h + 4*u]; s2[u] = (s > NN-1) ? 0 : s;
        }
        #pragma unroll
        for (int u = 0; u < 4; ++u)
            v2[u] = *reinterpret_cast<const float4*>(fbatch + s2[u]*DD + laneoff);
        #pragma unroll
        for (int u = 0; u < 4; ++u) {
            float mw = (32 + h + 4*u < cnt0) ? 1.f : 0.f;
            acc0.x += v2[u].x*mw; acc0.y += v2[u].y*mw;
            acc0.z += v2[u].z*mw; acc0.w += v2[u].w*mw;
        }
        for (int e = 48 + h; e < cnt0; e += 4) {
            int s = sp0[e];
            float4 v = *reinterpret_cast<const float4*>(fbatch + s*DD + laneoff);
            acc0.x += v.x; acc0.y += v.y; acc0.z += v.z; acc0.w += v.w;
        }
    }
    if (cnt1 > 32) {                     // wave-uniform
        float4 v2[4]; int s2[4];
        #pragma unroll
        for (int u = 0; u < 4; ++u) {
            int s = sp1[32 + h + 4*u]; s2[u] = (s > NN-1) ? 0 : s;
        }
        #pragma unroll
        for (int u = 0; u < 4; ++u)
            v2[u] = *reinterpret_cast<const float4*>(fbatch + s2[u]*DD + laneoff);
        #pragma unroll
        for (int u = 0; u < 4; ++u) {
            float mw = (32 + h + 4*u < cnt1) ? 1.f : 0.f;
            acc1.x += v2[u].x*mw; acc1.y += v2[u].y*mw;
            acc1.z += v2[u].z*mw; acc1.w += v2[u].w*mw;
        }
        for (int e = 48 + h; e < cnt1; e += 4) {
            int s = sp1[e];
            float4 v = *reinterpret_cast<const float4*>(fbatch + s*DD + laneoff);
            acc1.x += v.x; acc1.y += v.y; acc1.z += v.z; acc1.w += v.w;
        }
    }

    // butterfly: every lane ends with the full sums
    acc0.x += __shfl_xor(acc0.x, 16); acc0.y += __shfl_xor(acc0.y, 16);
    acc0.z += __shfl_xor(acc0.z, 16); acc0.w += __shfl_xor(acc0.w, 16);
    acc0.x += __shfl_xor(acc0.x, 32); acc0.y += __shfl_xor(acc0.y, 32);
    acc0.z += __shfl_xor(acc0.z, 32); acc0.w += __shfl_xor(acc0.w, 32);
    acc1.x += __shfl_xor(acc1.x, 16); acc1.y += __shfl_xor(acc1.y, 16);
    acc1.z += __shfl_xor(acc1.z, 16); acc1.w += __shfl_xor(acc1.w, 16);
    acc1.x += __shfl_xor(acc1.x, 32); acc1.y += __shfl_xor(acc1.y, 32);
    acc1.z += __shfl_xor(acc1.z, 32); acc1.w += __shfl_xor(acc1.w, 32);

    const float s = inv_denom();
    if (h == 0) {
        float4 o = make_float4(acc0.x*s, acc0.y*s, acc0.z*s, acc0.w*s);
        *reinterpret_cast<float4*>(fout + (size_t)g0*DD + laneoff) = o;
    } else if (h == 1) {
        float4 o = make_float4(acc1.x*s, acc1.y*s, acc1.z*s, acc1.w*s);
        *reinterpret_cast<float4*>(fout + (size_t)(g0+1)*DD + laneoff) = o;
    }
}

// ---------------------------------------------------------------------------
// Fused final stage, 64-row tiles (8x8 acc) with explicit register
// double-buffer prefetch of Bmat k-chunks (best measured: 41.6-42.1 us).
// ---------------------------------------------------------------------------
__global__ __launch_bounds__(256) void final_kernel(
        const float* __restrict__ x3, const float* __restrict__ x,
        const float* __restrict__ Bmat, const float* __restrict__ bout,
        float* __restrict__ out) {
    __shared__ float a_lds[64][DD];
    __shared__ float attn_lds[64];
    int t = threadIdx.x;
    int tc = t & 31, tr = t >> 5;       // tc: 8 cols each; tr: 8 rows each
    int row0 = blockIdx.x * 64;

    for (int u = t; u < 64*32; u += 256) {
        int r = u >> 5, cp = u & 31;
        *reinterpret_cast<float4*>(&a_lds[r][cp*4]) =
            *reinterpret_cast<const float4*>(x3 + (size_t)(row0 + r)*DD + cp*4);
    }
    if (t < 64) attn_lds[t] = 0.f;

    const float* bp = Bmat + tc*8;      // this thread's column slice
    float4 pa0[4], pa1[4], pb0[4], pb1[4];
    #pragma unroll
    for (int kk = 0; kk < 4; ++kk) {
        pa0[kk] = *reinterpret_cast<const float4*>(bp + kk*256);
        pa1[kk] = *reinterpret_cast<const float4*>(bp + kk*256 + 4);
    }
    __syncthreads();

    float acc[8][8];
    #pragma unroll
    for (int r = 0; r < 8; ++r)
        #pragma unroll
        for (int u = 0; u < 8; ++u) acc[r][u] = 0.f;

    #pragma unroll 1
    for (int k0 = 0; k0 < DD; k0 += 8) {
        int kn = (k0 + 4 < DD) ? (k0 + 4) : 0;
        #pragma unroll
        for (int kk = 0; kk < 4; ++kk) {
            pb0[kk] = *reinterpret_cast<const float4*>(bp + (kn+kk)*256);
            pb1[kk] = *reinterpret_cast<const float4*>(bp + (kn+kk)*256 + 4);
        }
        {
            float4 av[8];
            #pragma unroll
            for (int r = 0; r < 8; ++r)
                av[r] = *reinterpret_cast<const float4*>(&a_lds[tr*8 + r][k0]);
            #pragma unroll
            for (int kk = 0; kk < 4; ++kk) {
                #pragma unroll
                for (int r = 0; r < 8; ++r) {
                    float a = (kk == 0) ? av[r].x : (kk == 1) ? av[r].y
                            : (kk == 2) ? av[r].z : av[r].w;
                    acc[r][0] += a*pa0[kk].x; acc[r][1] += a*pa0[kk].y;
                    acc[r][2] += a*pa0[kk].z; acc[r][3] += a*pa0[kk].w;
                    acc[r][4] += a*pa1[kk].x; acc[r][5] += a*pa1[kk].y;
                    acc[r][6] += a*pa1[kk].z; acc[r][7] += a*pa1[kk].w;
                }
            }
        }
        int km = (k0 + 8 < DD) ? (k0 + 8) : 0;
        #pragma unroll
        for (int kk = 0; kk < 4; ++kk) {
            pa0[kk] = *reinterpret_cast<const float4*>(bp + (km+kk)*256);
            pa1[kk] = *reinterpret_cast<const float4*>(bp + (km+kk)*256 + 4);
        }
        {
            float4 av[8];
            #pragma unroll
            for (int r = 0; r < 8; ++r)
                av[r] = *reinterpret_cast<const float4*>(&a_lds[tr*8 + r][k0 + 4]);
            #pragma unroll
            for (int kk = 0; kk < 4; ++kk) {
                #pragma unroll
                for (int r = 0; r < 8; ++r) {
                    float a = (kk == 0) ? av[r].x : (kk == 1) ? av[r].y
                            : (kk == 2) ? av[r].z : av[r].w;
                    acc[r][0] += a*pb0[kk].x; acc[r][1] += a*pb0[kk].y;
                    acc[r][2] += a*pb0[kk].z; acc[r][3] += a*pb0[kk].w;
                    acc[r][4] += a*pb1[kk].x; acc[r][5] += a*pb1[kk].y;
                    acc[r][6] += a*pb1[kk].z; acc[r][7] += a*pb1[kk].w;
                }
            }
        }
    }

    if (tc < 16) {
        #pragma unroll
        for (int r = 0; r < 8; ++r) {
            int row = row0 + tr*8 + r;
            const float4 xa = *reinterpret_cast<const float4*>(x + (size_t)row*DD + tc*8);
            const float4 xb = *reinterpret_cast<const float4*>(x + (size_t)row*DD + tc*8 + 4);
            float p = xa.x*acc[r][0] + xa.y*acc[r][1] + xa.z*acc[r][2] + xa.w*acc[r][3]
                    + xb.x*acc[r][4] + xb.y*acc[r][5] + xb.z*acc[r][6] + xb.w*acc[r][7];
            atomicAdd(&attn_lds[tr*8 + r], p);
        }
    }
    __syncthreads();

    if (tc >= 16) {
        int c0 = (tc - 16) * 8;
        float4 ba  = *reinterpret_cast<const float4*>(bout + c0);
        float4 bbv = *reinterpret_cast<const float4*>(bout + c0 + 4);
        #pragma unroll
        for (int r = 0; r < 8; ++r) {
            int row = row0 + tr*8 + r;
            float at = attn_lds[tr*8 + r];
            float4 o0, o1;
            o0.x = at*acc[r][0] + ba.x;  o0.y = at*acc[r][1] + ba.y;
            o0.z = at*acc[r][2] + ba.z;  o0.w = at*acc[r][3] + ba.w;
            o1.x = at*acc[r][4] + bbv.x; o1.y = at*acc[r][5] + bbv.y;
            o1.z = at*acc[r][6] + bbv.z; o1.w = at*acc[r][7] + bbv.w;
            *reinterpret_cast<float4*>(out + (size_t)row*DD + c0)     = o0;
            *reinterpret_cast<float4*>(out + (size_t)row*DD + c0 + 4) = o1;
        }
    }
}

// ---------------------------------------------------------------------------
// ws layout (~24.3 MB; measured ws_size ~268 MB):
//   f_a     @ 0         16777216 B   (x3 ping buffer)
//   srcs16  @ 16777216   2359552 B   (256*4608 u16 + pad)
//   meta    @ 19136768    131072 B   (packed (off<<8)|cnt)
//   (spare) @ 19267840    131072 B
//   Bmat    @ 19398912    131072 B
//   staging @ 19529984   4718592 B   (256*4608 int)
//   gcursor @ 24248576      1024 B
// ---------------------------------------------------------------------------
extern "C" void kernel_launch(void* const* d_in, const int* in_sizes, int n_in,
                              void* d_out, int out_size, void* d_ws, size_t ws_size,
                              hipStream_t stream) {
    const float* x    = (const float*)d_in[0];
    const int*   idx  = (const int*)  d_in[1];
    const float* Wqkv = (const float*)d_in[2];
    const float* Wout = (const float*)d_in[3];
    const float* bout = (const float*)d_in[4];
    float* out = (float*)d_out;

    char* ws = (char*)d_ws;
    float*          f_a     = (float*)(ws);
    unsigned short* srcs16  = (unsigned short*)(ws + 16777216);
    int*            meta    = (int*)(ws + 19136768);
    float*          Bmat    = (float*)(ws + 19398912);
    int*            staging = (int*)(ws + 19529984);
    int*            gcursor = (int*)(ws + 24248576);

    compute_bmat<<<DD, 256, 0, stream>>>(Wqkv, Wout, Bmat, gcursor);
    partition_kernel<<<1024, 256, 0, stream>>>(idx, staging, gcursor);
    bin_kernel<<<NRANGE, 512, 0, stream>>>(staging, gcursor, srcs16, meta);

    hop_kernel<<<8192, 256, 0, stream>>>(x,   f_a, meta, srcs16);
    hop_kernel<<<8192, 256, 0, stream>>>(f_a, out, meta, srcs16);
    hop_kernel<<<8192, 256, 0, stream>>>(out, f_a, meta, srcs16);

    final_kernel<<<BN/64, 256, 0, stream>>>(f_a, x, Bmat, bout, out);
}